// Round 20
// baseline (59.879 us; speedup 1.0000x reference)
//
#include <hip/hip_runtime.h>
#include <hip/hip_bf16.h>

// ---------------------------------------------------------------------------
// QuadAttention via Hadamard/flash form:
//   out[n,j] = sum_m (q1k1^T)[n,m]*(q2k2^T)[n,m]*(q3k3^T)[n,m]*v[m,j]
// f16 inputs, fp32 accum. B=2, N=2048, C=256, H=16, D=16.
// k_attn: LDS-free, barrier-free, pswap-free; XCD swizzle; nn=4 (wave covers
// 128 n) so each K/V load feeds 20 MFMAs -> half the VMEM per MFMA.
// ---------------------------------------------------------------------------

typedef _Float16 f16;
typedef _Float16 f16x8 __attribute__((ext_vector_type(8)));
typedef _Float16 f16x4 __attribute__((ext_vector_type(4)));
typedef float    f32x16 __attribute__((ext_vector_type(16)));
typedef uint32_t u32x4 __attribute__((ext_vector_type(4)));

#define MFMA32(a, b, c) __builtin_amdgcn_mfma_f32_32x32x16_f16((a), (b), (c), 0, 0, 0)

// ws layout (bytes)
constexpr size_t OFF_XH  = 0;          // f16 [4096][256]
constexpr size_t OFF_WH  = 2097152;    // f16 [7][256][256]  (W+I, *scale for t>=3)
constexpr size_t OFF_BSC = 3014656;    // f32 [7][256]
constexpr size_t OFF_GH  = 3021824;    // f16 [256][256]     (Wo .* gamma)
constexpr size_t OFF_RSG = 3152896;    // f32 [256]
constexpr size_t OFF_B2  = 3153920;    // f32 [256]
constexpr size_t OFF_Y   = 3154944;    // f16 [3][4096][256] q1,q2,q3 row-major
constexpr size_t OFF_KH  = 9446400;    // f16 [3][32][2048][16]  k1,k2,k3 per-head packed
constexpr size_t OFF_VT  = 15737856;   // f16 [32][256][16][8]   v tiled, m-permuted
constexpr size_t OFF_OPP = 17835008;   // f16 [4][4096][256] split-m partials (8MB)

struct W7 { const float* W[7]; const float* b[7]; };

// Swizzled [R][64]-f16 tile helpers (for GEMM kernels)
__device__ __forceinline__ int toff(int row, int oct) {
    return row * 128 + (((oct) ^ (row & 7)) << 4);
}
__device__ __forceinline__ f16x8 ldfrag(const f16* base, int row, int oct) {
    return *(const f16x8*)((const char*)base + toff(row, oct));
}
__device__ __forceinline__ void stfrag(f16* base, int row, int oct, f16x8 v) {
    *(f16x8*)((char*)base + toff(row, oct)) = v;
}
// C/D layout of mfma_f32_32x32x16: col = lane&31, row = (reg&3)+8*(reg>>2)+4*(lane>>5)
__device__ __forceinline__ int drow(int reg, int l) {
    return (reg & 3) + ((reg >> 2) << 3) + ((l >> 5) << 2);
}
__device__ __forceinline__ void zero16(f32x16& v) {
#pragma unroll
    for (int i = 0; i < 16; ++i) v[i] = 0.f;
}
__device__ __forceinline__ uint32_t pkrtz(float a, float b) {
    auto h = __builtin_amdgcn_cvt_pkrtz(a, b);   // __fp16 ext_vector(2)
    return __builtin_bit_cast(uint32_t, h);
}

// ---------------- k_prep: conversions + W+I + scale + LN-fold prep ----------
__global__ __launch_bounds__(256) void k_prep(const float* __restrict__ x, W7 p,
                                              float scale,
                                              const float* __restrict__ Wo,
                                              const float* __restrict__ bo,
                                              const float* __restrict__ gamma,
                                              const float* __restrict__ beta,
                                              char* ws) {
    const int bid = blockIdx.x;
    if (bid < 2824) {
        f16* xh  = (f16*)(ws + OFF_XH);
        f16* Wh  = (f16*)(ws + OFF_WH);
        float* bsc = (float*)(ws + OFF_BSC);
        int idx = bid * 256 + threadIdx.x;
        if (idx < 262144) {                        // x -> xh
            float4 v = ((const float4*)x)[idx];
            f16x4 o; o[0] = (f16)v.x; o[1] = (f16)v.y; o[2] = (f16)v.z; o[3] = (f16)v.w;
            *(f16x4*)(xh + (size_t)idx * 4) = o;
        } else if (idx < 262144 + 458752) {        // W' = (W+I)*(t>=3?scale:1)
            int r = idx - 262144;
            int t = r >> 16, cc = r & 65535, c = cc >> 8, k = cc & 255;
            float v = p.W[t][cc] + (c == k ? 1.f : 0.f);
            if (t >= 3) v *= scale;
            Wh[r] = (f16)v;
        } else if (idx < 262144 + 458752 + 1792) { // scaled bias
            int r = idx - 262144 - 458752;
            int t = r >> 8;
            bsc[r] = p.b[t][r & 255] * (t >= 3 ? scale : 1.f);
        }
    } else {                                       // LN-fold
        f16* Gh = (f16*)(ws + OFF_GH);
        float* rsg = (float*)(ws + OFF_RSG);
        float* B2  = (float*)(ws + OFF_B2);
        int c2 = bid - 2824, c = threadIdx.x;
        float wv = Wo[c2 * 256 + c];
        float g = gamma[c] * wv;
        float bb = beta[c] * wv;
        Gh[c2 * 256 + c] = (f16)g;
        __shared__ float sg[4], sb[4];
#pragma unroll
        for (int off = 32; off > 0; off >>= 1) { g += __shfl_down(g, off); bb += __shfl_down(bb, off); }
        if ((c & 63) == 0) { sg[c >> 6] = g; sb[c >> 6] = bb; }
        __syncthreads();
        if (c == 0) {
            rsg[c2] = sg[0] + sg[1] + sg[2] + sg[3];
            B2[c2]  = sb[0] + sb[1] + sb[2] + sb[3] + bo[c2];
        }
    }
}

// ---------------- k_lin7: 7 fused linears ------------------------------------
// All t computed row-major D[n][c]; epilogue routes stores:
//   t<3 -> Y row-major;  t=3..5 -> Kh [t-3][bh][m][16d];
//   t=6 -> Vt with m-permutation (swap bits 2,3 of m&15).
__global__ __launch_bounds__(512) void k_lin7(const float* __restrict__ mask, char* ws) {
    const f16* xh = (const f16*)(ws + OFF_XH);
    const f16* Wh = (const f16*)(ws + OFF_WH);
    const float* bsc = (const float*)(ws + OFF_BSC);
    f16* Y  = (f16*)(ws + OFF_Y);
    f16* Kh = (f16*)(ws + OFF_KH);
    f16* Vt = (f16*)(ws + OFF_VT);

    const int ct = blockIdx.x;            // 0..13
    const int rt = blockIdx.y;            // 0..31
    const int t = ct >> 1, half = ct & 1;
    const int tid = threadIdx.x, l = tid & 63, w = tid >> 6;
    const int wr = w >> 1, wc = w & 1;    // wave tile: 32 rows x 64 cols

    __shared__ f16 Xl[128 * 64];
    __shared__ f16 Wl[128 * 64];

    f32x16 acc[2];
    zero16(acc[0]); zero16(acc[1]);

    const f16* Wt = Wh + (size_t)t * 65536;
    for (int kt = 0; kt < 4; ++kt) {
        __syncthreads();
#pragma unroll
        for (int e = 0; e < 2; ++e) {
            int g = tid + 512 * e;        // 0..1023
            int row = g >> 3, oct = g & 7;
            f16x8 vx = *(const f16x8*)(xh + (size_t)(rt * 128 + row) * 256 + kt * 64 + oct * 8);
            stfrag(Xl, row, oct, vx);
            f16x8 vw = *(const f16x8*)(Wt + (size_t)(half * 128 + row) * 256 + kt * 64 + oct * 8);
            stfrag(Wl, row, oct, vw);
        }
        __syncthreads();
#pragma unroll
        for (int s = 0; s < 4; ++s) {
            int g = s * 2 + (l >> 5);
            f16x8 a0 = ldfrag(Xl, wr * 32 + (l & 31), g);
            f16x8 b0 = ldfrag(Wl, wc * 64 + (l & 31), g);
            f16x8 b1 = ldfrag(Wl, wc * 64 + 32 + (l & 31), g);
            acc[0] = MFMA32(a0, b0, acc[0]);
            acc[1] = MFMA32(a0, b1, acc[1]);
        }
    }

#pragma unroll
    for (int mc = 0; mc < 2; ++mc)
#pragma unroll
        for (int reg = 0; reg < 16; ++reg) {
            int n = rt * 128 + wr * 32 + drow(reg, l);
            int c = half * 128 + wc * 64 + mc * 32 + (l & 31);
            float v = (acc[mc][reg] + bsc[t * 256 + c]) * mask[n];
            f16 hv = (f16)v;
            if (t < 3) {
                Y[(size_t)t * 1048576 + (size_t)n * 256 + c] = hv;
            } else {
                int bb = n >> 11, m = n & 2047, h16 = c >> 4, d = c & 15;
                int bhx = bb * 16 + h16;
                if (t < 6) {
                    Kh[((size_t)(t - 3) * 32 + bhx) * 32768 + m * 16 + d] = hv;
                } else {
                    int m15 = m & 15;
                    int mp = (m & ~15) | (m15 & 3) | ((m15 & 4) << 1) | ((m15 & 8) >> 1);
                    Vt[(size_t)bhx * 32768 + (mp >> 3) * 128 + d * 8 + (mp & 7)] = hv;
                }
            }
        }
}

// ---------------- k_attn: LDS-free, barrier-free Hadamard attention ---------
// Wave covers 128 n (4 groups of 32); m streamed in 32-chunks; split-m=4.
// Each 5-load chunk feeds 20 MFMAs (VMEM/MFMA halved vs nn=2).
__global__ __launch_bounds__(256, 2) void k_attn(char* ws) {
    const f16* Y  = (const f16*)(ws + OFF_Y);
    const f16* Kh = (const f16*)(ws + OFF_KH);
    const f16* Vt = (const f16*)(ws + OFF_VT);
    f16* OPP = (f16*)(ws + OFF_OPP);

    // bijective XCD-chunk swizzle (512 blocks = 8 XCD x 64); the 4 nt-blocks
    // sharing (bh,ms) are consecutive works -> same XCD L2.
    const int lin = blockIdx.x + 4 * (blockIdx.y + 32 * blockIdx.z);
    const int work = (lin & 7) * 64 + (lin >> 3);
    const int nt = work & 3;              // 0..3
    const int bh = (work >> 2) & 31;      // 0..31
    const int ms = work >> 7;             // 0..3 split-m

    const int b = bh >> 4, hb = (bh & 15) * 16;
    const int tid = threadIdx.x, l = tid & 63, w = tid >> 6;
    const int lane31 = l & 31, lhi = l >> 5;
    const int n0 = nt * 512 + w * 128;    // wave's n-base within batch
    const int jj = lane31 & 15;           // mirror for lanes>=16 (broadcast)

    // hoisted q-frags: col = lane31 = n, k-slice = lhi*8 in d
    f16x8 qf[3][4];
#pragma unroll
    for (int t = 0; t < 3; ++t)
#pragma unroll
        for (int nn = 0; nn < 4; ++nn)
            qf[t][nn] = *(const f16x8*)(Y + (size_t)t * 1048576 +
                        ((size_t)(b * 2048 + n0 + nn * 32 + lane31)) * 256 + hb + lhi * 8);

    f32x16 acc[4];
#pragma unroll
    for (int nn = 0; nn < 4; ++nn) zero16(acc[nn]);
    f32x16 zzz; zero16(zzz);

    // coalesced per-lane bases (f16 units); chunk stride = 512 f16 (1KB)
    const f16* Kb0 = Kh + (size_t)bh * 32768 + (ms * 512 + lane31) * 16 + lhi * 8;
    const f16* Kb1 = Kb0 + 1048576;
    const f16* Kb2 = Kb1 + 1048576;
    const f16* Vb  = Vt + (size_t)bh * 32768 + ms * 8192 + lhi * 128 + jj * 8;

    // 1-deep prefetch
    f16x8 kf0n = *(const f16x8*)(Kb0);
    f16x8 kf1n = *(const f16x8*)(Kb1);
    f16x8 kf2n = *(const f16x8*)(Kb2);
    f16x8 bv1n = *(const f16x8*)(Vb);
    f16x8 bv2n = *(const f16x8*)(Vb + 256);

    for (int c = 0; c < 16; ++c) {
        f16x8 kf0 = kf0n, kf1 = kf1n, kf2 = kf2n, bv1 = bv1n, bv2 = bv2n;
        if (c < 15) {                      // issue next chunk's loads NOW
            const int o = (c + 1) * 512;
            kf0n = *(const f16x8*)(Kb0 + o);
            kf1n = *(const f16x8*)(Kb1 + o);
            kf2n = *(const f16x8*)(Kb2 + o);
            bv1n = *(const f16x8*)(Vb + o);
            bv2n = *(const f16x8*)(Vb + o + 256);
        }
        __builtin_amdgcn_s_setprio(1);
#pragma unroll
        for (int nn = 0; nn < 4; ++nn) {
            f32x16 D1 = MFMA32(kf0, qf[0][nn], zzz);   // D[m=drow][n=lane31]
            f32x16 D2 = MFMA32(kf1, qf[1][nn], zzz);
            f32x16 D3 = MFMA32(kf2, qf[2][nn], zzz);
            D1 *= D2;
            D1 *= D3;
            // no permlane: k->m permutation is lane-uniform and folded into Vt
            uint32_t p01 = pkrtz(D1[0], D1[1]),   p23 = pkrtz(D1[2], D1[3]);
            uint32_t p45 = pkrtz(D1[4], D1[5]),   p67 = pkrtz(D1[6], D1[7]);
            uint32_t p89 = pkrtz(D1[8], D1[9]),   pAB = pkrtz(D1[10], D1[11]);
            uint32_t pCD = pkrtz(D1[12], D1[13]), pEF = pkrtz(D1[14], D1[15]);
            u32x4 A1 = {p01, p23, p45, p67};
            u32x4 A2 = {p89, pAB, pCD, pEF};
            acc[nn] = MFMA32(__builtin_bit_cast(f16x8, A1), bv1, acc[nn]);
            acc[nn] = MFMA32(__builtin_bit_cast(f16x8, A2), bv2, acc[nn]);
        }
        __builtin_amdgcn_s_setprio(0);
    }

    // epilogue: acc row = n (drow), col = j (lane31, valid < 16)
    if (lane31 < 16) {
        f16* outp = OPP + (size_t)ms * 1048576;
#pragma unroll
        for (int nn = 0; nn < 4; ++nn)
#pragma unroll
            for (int reg = 0; reg < 16; ++reg) {
                int n = n0 + nn * 32 + drow(reg, l);
                outp[((size_t)(b * 2048) + n) * 256 + hb + lane31] = (f16)acc[nn][reg];
            }
    }
}

// ---------------- k_final: out = LN(sum P0..P3) @ Wo^T + bo, 64x64 tiles ----
__global__ __launch_bounds__(256) void k_final(float* __restrict__ out, char* ws) {
    const f16* P0 = (const f16*)(ws + OFF_OPP);
    const f16* P1 = P0 + 1048576;
    const f16* P2 = P1 + 1048576;
    const f16* P3 = P2 + 1048576;
    const f16* Gh = (const f16*)(ws + OFF_GH);
    const float* rsg = (const float*)(ws + OFF_RSG);
    const float* B2 = (const float*)(ws + OFF_B2);

    const int ct = blockIdx.x;            // 0..3  (64 output cols)
    const int rt = blockIdx.y;            // 0..63 (64 rows)
    const int tid = threadIdx.x, l = tid & 63, w = tid >> 6;
    const int wr = w >> 1, wc = w & 1;    // wave-tile 32 rows x 32 cols

    __shared__ f16 Xl[64 * 64];
    __shared__ f16 Wl[64 * 64];
    __shared__ float muL[64], rsL[64];

    float sum[2] = {0.f, 0.f}, sumsq[2] = {0.f, 0.f};

    f32x16 acc; zero16(acc);

    for (int kt = 0; kt < 4; ++kt) {
        __syncthreads();
#pragma unroll
        for (int e = 0; e < 2; ++e) {
            int g = tid + 256 * e;        // 0..511 = 64 rows x 8 octs
            int row = g >> 3, oct = g & 7;
            size_t idx = (size_t)(rt * 64 + row) * 256 + kt * 64 + oct * 8;
            f16x8 va = *(const f16x8*)(P0 + idx);
            f16x8 vb = *(const f16x8*)(P1 + idx);
            f16x8 vc = *(const f16x8*)(P2 + idx);
            f16x8 vd = *(const f16x8*)(P3 + idx);
            f16x8 vx;
#pragma unroll
            for (int q = 0; q < 8; ++q) {
                float f = ((float)va[q] + (float)vb[q]) + ((float)vc[q] + (float)vd[q]);
                vx[q] = (f16)f;
                sum[e] += f; sumsq[e] += f * f;
            }
            stfrag(Xl, row, oct, vx);
            f16x8 vw = *(const f16x8*)(Gh + (size_t)(ct * 64 + row) * 256 + kt * 64 + oct * 8);
            stfrag(Wl, row, oct, vw);
        }
        __syncthreads();
#pragma unroll
        for (int s = 0; s < 4; ++s) {
            int g = s * 2 + (l >> 5);
            f16x8 a0 = ldfrag(Xl, wr * 32 + (l & 31), g);
            f16x8 b0 = ldfrag(Wl, wc * 32 + (l & 31), g);
            acc = MFMA32(a0, b0, acc);
        }
    }

    // row stats: 8 threads (same tid>>3) share each row; rows tid>>3, +32
#pragma unroll
    for (int e = 0; e < 2; ++e) {
#pragma unroll
        for (int off = 1; off < 8; off <<= 1) {
            sum[e] += __shfl_xor(sum[e], off);
            sumsq[e] += __shfl_xor(sumsq[e], off);
        }
    }
    if ((tid & 7) == 0) {
#pragma unroll
        for (int e = 0; e < 2; ++e) {
            int row = (tid >> 3) + 32 * e;
            float m = sum[e] * (1.f / 256.f);
            float var = sumsq[e] * (1.f / 256.f) - m * m;
            muL[row] = m;
            rsL[row] = rsqrtf(var + 1e-5f);
        }
    }
    __syncthreads();

#pragma unroll
    for (int reg = 0; reg < 16; ++reg) {
        int nloc = wr * 32 + drow(reg, l);
        int n = rt * 64 + nloc;
        int c2 = ct * 64 + wc * 32 + (l & 31);
        float v = rsL[nloc] * (acc[reg] - muL[nloc] * rsg[c2]) + B2[c2];
        out[(size_t)n * 256 + c2] = v;
    }
}

// ---------------------------------------------------------------------------
extern "C" void kernel_launch(void* const* d_in, const int* in_sizes, int n_in,
                              void* d_out, int out_size, void* d_ws, size_t ws_size,
                              hipStream_t stream) {
    (void)in_sizes; (void)n_in; (void)out_size; (void)ws_size;
    const float* x    = (const float*)d_in[0];
    const float* mask = (const float*)d_in[1];
    W7 p;
    for (int t = 0; t < 7; ++t) {
        p.W[t] = (const float*)d_in[2 + 2 * t];
        p.b[t] = (const float*)d_in[3 + 2 * t];
    }
    const float* Wo    = (const float*)d_in[16];
    const float* bo    = (const float*)d_in[17];
    const float* gamma = (const float*)d_in[18];
    const float* beta  = (const float*)d_in[19];
    char* ws = (char*)d_ws;

    const float scale = 0.14865088937534013f;   // 2048^(-0.25)

    k_prep <<<3080, 256, 0, stream>>>(x, p, scale, Wo, bo, gamma, beta, ws);
    k_lin7 <<<dim3(14, 32), 512, 0, stream>>>(mask, ws);
    k_attn <<<dim3(4, 32, 4), 256, 0, stream>>>(ws);
    k_final<<<dim3(4, 64), 256, 0, stream>>>((float*)d_out, ws);
}

// Round 21
// 57.177 us; speedup vs baseline: 1.0472x; 1.0472x over previous
//
#include <hip/hip_runtime.h>
#include <hip/hip_bf16.h>

// ---------------------------------------------------------------------------
// QuadAttention via Hadamard/flash form:
//   out[n,j] = sum_m (q1k1^T)[n,m]*(q2k2^T)[n,m]*(q3k3^T)[n,m]*v[m,j]
// f16 inputs, fp32 accum. B=2, N=2048, C=256, H=16, D=16.
// k_attn: LDS-free, barrier-free, pswap-free; XCD swizzle; 2-deep prefetch;
// dual PV accumulators; s_setprio around compute. k_final: 64x64 tiles
// (256 blocks -> full CU coverage).  [best-measured config, R19: 57.6 us]
// ---------------------------------------------------------------------------

typedef _Float16 f16;
typedef _Float16 f16x8 __attribute__((ext_vector_type(8)));
typedef _Float16 f16x4 __attribute__((ext_vector_type(4)));
typedef float    f32x16 __attribute__((ext_vector_type(16)));
typedef uint32_t u32x4 __attribute__((ext_vector_type(4)));

#define MFMA32(a, b, c) __builtin_amdgcn_mfma_f32_32x32x16_f16((a), (b), (c), 0, 0, 0)

// ws layout (bytes)
constexpr size_t OFF_XH  = 0;          // f16 [4096][256]
constexpr size_t OFF_WH  = 2097152;    // f16 [7][256][256]  (W+I, *scale for t>=3)
constexpr size_t OFF_BSC = 3014656;    // f32 [7][256]
constexpr size_t OFF_GH  = 3021824;    // f16 [256][256]     (Wo .* gamma)
constexpr size_t OFF_RSG = 3152896;    // f32 [256]
constexpr size_t OFF_B2  = 3153920;    // f32 [256]
constexpr size_t OFF_Y   = 3154944;    // f16 [3][4096][256] q1,q2,q3 row-major
constexpr size_t OFF_KH  = 9446400;    // f16 [3][32][2048][16]  k1,k2,k3 per-head packed
constexpr size_t OFF_VT  = 15737856;   // f16 [32][256][16][8]   v tiled, m-permuted
constexpr size_t OFF_OPP = 17835008;   // f16 [2][4096][256] split-m partials

struct W7 { const float* W[7]; const float* b[7]; };

// Swizzled [R][64]-f16 tile helpers (for GEMM kernels)
__device__ __forceinline__ int toff(int row, int oct) {
    return row * 128 + (((oct) ^ (row & 7)) << 4);
}
__device__ __forceinline__ f16x8 ldfrag(const f16* base, int row, int oct) {
    return *(const f16x8*)((const char*)base + toff(row, oct));
}
__device__ __forceinline__ void stfrag(f16* base, int row, int oct, f16x8 v) {
    *(f16x8*)((char*)base + toff(row, oct)) = v;
}
// C/D layout of mfma_f32_32x32x16: col = lane&31, row = (reg&3)+8*(reg>>2)+4*(lane>>5)
__device__ __forceinline__ int drow(int reg, int l) {
    return (reg & 3) + ((reg >> 2) << 3) + ((l >> 5) << 2);
}
__device__ __forceinline__ void zero16(f32x16& v) {
#pragma unroll
    for (int i = 0; i < 16; ++i) v[i] = 0.f;
}
__device__ __forceinline__ uint32_t pkrtz(float a, float b) {
    auto h = __builtin_amdgcn_cvt_pkrtz(a, b);   // __fp16 ext_vector(2)
    return __builtin_bit_cast(uint32_t, h);
}

// ---------------- k_prep: conversions + W+I + scale + LN-fold prep ----------
__global__ __launch_bounds__(256) void k_prep(const float* __restrict__ x, W7 p,
                                              float scale,
                                              const float* __restrict__ Wo,
                                              const float* __restrict__ bo,
                                              const float* __restrict__ gamma,
                                              const float* __restrict__ beta,
                                              char* ws) {
    const int bid = blockIdx.x;
    if (bid < 2824) {
        f16* xh  = (f16*)(ws + OFF_XH);
        f16* Wh  = (f16*)(ws + OFF_WH);
        float* bsc = (float*)(ws + OFF_BSC);
        int idx = bid * 256 + threadIdx.x;
        if (idx < 262144) {                        // x -> xh
            float4 v = ((const float4*)x)[idx];
            f16x4 o; o[0] = (f16)v.x; o[1] = (f16)v.y; o[2] = (f16)v.z; o[3] = (f16)v.w;
            *(f16x4*)(xh + (size_t)idx * 4) = o;
        } else if (idx < 262144 + 458752) {        // W' = (W+I)*(t>=3?scale:1)
            int r = idx - 262144;
            int t = r >> 16, cc = r & 65535, c = cc >> 8, k = cc & 255;
            float v = p.W[t][cc] + (c == k ? 1.f : 0.f);
            if (t >= 3) v *= scale;
            Wh[r] = (f16)v;
        } else if (idx < 262144 + 458752 + 1792) { // scaled bias
            int r = idx - 262144 - 458752;
            int t = r >> 8;
            bsc[r] = p.b[t][r & 255] * (t >= 3 ? scale : 1.f);
        }
    } else {                                       // LN-fold
        f16* Gh = (f16*)(ws + OFF_GH);
        float* rsg = (float*)(ws + OFF_RSG);
        float* B2  = (float*)(ws + OFF_B2);
        int c2 = bid - 2824, c = threadIdx.x;
        float wv = Wo[c2 * 256 + c];
        float g = gamma[c] * wv;
        float bb = beta[c] * wv;
        Gh[c2 * 256 + c] = (f16)g;
        __shared__ float sg[4], sb[4];
#pragma unroll
        for (int off = 32; off > 0; off >>= 1) { g += __shfl_down(g, off); bb += __shfl_down(bb, off); }
        if ((c & 63) == 0) { sg[c >> 6] = g; sb[c >> 6] = bb; }
        __syncthreads();
        if (c == 0) {
            rsg[c2] = sg[0] + sg[1] + sg[2] + sg[3];
            B2[c2]  = sb[0] + sb[1] + sb[2] + sb[3] + bo[c2];
        }
    }
}

// ---------------- k_lin7: 7 fused linears ------------------------------------
// All t computed row-major D[n][c]; epilogue routes stores:
//   t<3 -> Y row-major;  t=3..5 -> Kh [t-3][bh][m][16d];
//   t=6 -> Vt with m-permutation (swap bits 2,3 of m&15).
__global__ __launch_bounds__(512) void k_lin7(const float* __restrict__ mask, char* ws) {
    const f16* xh = (const f16*)(ws + OFF_XH);
    const f16* Wh = (const f16*)(ws + OFF_WH);
    const float* bsc = (const float*)(ws + OFF_BSC);
    f16* Y  = (f16*)(ws + OFF_Y);
    f16* Kh = (f16*)(ws + OFF_KH);
    f16* Vt = (f16*)(ws + OFF_VT);

    const int ct = blockIdx.x;            // 0..13
    const int rt = blockIdx.y;            // 0..31
    const int t = ct >> 1, half = ct & 1;
    const int tid = threadIdx.x, l = tid & 63, w = tid >> 6;
    const int wr = w >> 1, wc = w & 1;    // wave tile: 32 rows x 64 cols

    __shared__ f16 Xl[128 * 64];
    __shared__ f16 Wl[128 * 64];

    f32x16 acc[2];
    zero16(acc[0]); zero16(acc[1]);

    const f16* Wt = Wh + (size_t)t * 65536;
    for (int kt = 0; kt < 4; ++kt) {
        __syncthreads();
#pragma unroll
        for (int e = 0; e < 2; ++e) {
            int g = tid + 512 * e;        // 0..1023
            int row = g >> 3, oct = g & 7;
            f16x8 vx = *(const f16x8*)(xh + (size_t)(rt * 128 + row) * 256 + kt * 64 + oct * 8);
            stfrag(Xl, row, oct, vx);
            f16x8 vw = *(const f16x8*)(Wt + (size_t)(half * 128 + row) * 256 + kt * 64 + oct * 8);
            stfrag(Wl, row, oct, vw);
        }
        __syncthreads();
#pragma unroll
        for (int s = 0; s < 4; ++s) {
            int g = s * 2 + (l >> 5);
            f16x8 a0 = ldfrag(Xl, wr * 32 + (l & 31), g);
            f16x8 b0 = ldfrag(Wl, wc * 64 + (l & 31), g);
            f16x8 b1 = ldfrag(Wl, wc * 64 + 32 + (l & 31), g);
            acc[0] = MFMA32(a0, b0, acc[0]);
            acc[1] = MFMA32(a0, b1, acc[1]);
        }
    }

#pragma unroll
    for (int mc = 0; mc < 2; ++mc)
#pragma unroll
        for (int reg = 0; reg < 16; ++reg) {
            int n = rt * 128 + wr * 32 + drow(reg, l);
            int c = half * 128 + wc * 64 + mc * 32 + (l & 31);
            float v = (acc[mc][reg] + bsc[t * 256 + c]) * mask[n];
            f16 hv = (f16)v;
            if (t < 3) {
                Y[(size_t)t * 1048576 + (size_t)n * 256 + c] = hv;
            } else {
                int bb = n >> 11, m = n & 2047, h16 = c >> 4, d = c & 15;
                int bhx = bb * 16 + h16;
                if (t < 6) {
                    Kh[((size_t)(t - 3) * 32 + bhx) * 32768 + m * 16 + d] = hv;
                } else {
                    int m15 = m & 15;
                    int mp = (m & ~15) | (m15 & 3) | ((m15 & 4) << 1) | ((m15 & 8) >> 1);
                    Vt[(size_t)bhx * 32768 + (mp >> 3) * 128 + d * 8 + (mp & 7)] = hv;
                }
            }
        }
}

// ---------------- k_attn: LDS-free, barrier-free Hadamard attention ---------
__global__ __launch_bounds__(256, 2) void k_attn(char* ws) {
    const f16* Y  = (const f16*)(ws + OFF_Y);
    const f16* Kh = (const f16*)(ws + OFF_KH);
    const f16* Vt = (const f16*)(ws + OFF_VT);
    f16* OPP = (f16*)(ws + OFF_OPP);

    // bijective XCD-chunk swizzle (512 blocks = 8 XCD x 64)
    const int lin = blockIdx.x + 8 * (blockIdx.y + 32 * blockIdx.z);
    const int work = (lin & 7) * 64 + (lin >> 3);
    const int nt = work & 7;              // 0..7
    const int bh = (work >> 3) & 31;      // 0..31
    const int ms = work >> 8;             // 0..1 split-m

    const int b = bh >> 4, hb = (bh & 15) * 16;
    const int tid = threadIdx.x, l = tid & 63, w = tid >> 6;
    const int lane31 = l & 31, lhi = l >> 5;
    const int n0 = nt * 256 + w * 64;     // wave's n-base within batch
    const int jj = lane31 & 15;           // mirror for lanes>=16 (broadcast)

    // hoisted q-frags: col = lane31 = n, k-slice = lhi*8 in d
    f16x8 qf[3][2];
#pragma unroll
    for (int t = 0; t < 3; ++t)
#pragma unroll
        for (int nn = 0; nn < 2; ++nn)
            qf[t][nn] = *(const f16x8*)(Y + (size_t)t * 1048576 +
                        ((size_t)(b * 2048 + n0 + nn * 32 + lane31)) * 256 + hb + lhi * 8);

    // dual accumulators per nn
    f32x16 accA[2], accB[2];
    zero16(accA[0]); zero16(accA[1]);
    zero16(accB[0]); zero16(accB[1]);
    f32x16 zzz; zero16(zzz);

    // coalesced per-lane bases (f16 units); chunk stride = 512 f16 (1KB)
    const f16* Kb0 = Kh + (size_t)bh * 32768 + (ms * 1024 + lane31) * 16 + lhi * 8;
    const f16* Kb1 = Kb0 + 1048576;
    const f16* Kb2 = Kb1 + 1048576;
    const f16* Vb  = Vt + (size_t)bh * 32768 + ms * 16384 + lhi * 128 + jj * 8;

    // 2-deep prefetch pipeline
    f16x8 kf0p[2], kf1p[2], kf2p[2], bv1p[2], bv2p[2];
#pragma unroll
    for (int s = 0; s < 2; ++s) {
        const int o = s * 512;
        kf0p[s] = *(const f16x8*)(Kb0 + o);
        kf1p[s] = *(const f16x8*)(Kb1 + o);
        kf2p[s] = *(const f16x8*)(Kb2 + o);
        bv1p[s] = *(const f16x8*)(Vb + o);
        bv2p[s] = *(const f16x8*)(Vb + o + 256);
    }

#pragma unroll 2
    for (int c = 0; c < 32; ++c) {
        const int slot = c & 1;
        f16x8 kf0 = kf0p[slot], kf1 = kf1p[slot], kf2 = kf2p[slot];
        f16x8 bv1 = bv1p[slot], bv2 = bv2p[slot];
        if (c < 30) {                      // refill slot with chunk c+2
            const int o = (c + 2) * 512;
            kf0p[slot] = *(const f16x8*)(Kb0 + o);
            kf1p[slot] = *(const f16x8*)(Kb1 + o);
            kf2p[slot] = *(const f16x8*)(Kb2 + o);
            bv1p[slot] = *(const f16x8*)(Vb + o);
            bv2p[slot] = *(const f16x8*)(Vb + o + 256);
        }
        __builtin_amdgcn_s_setprio(1);     // T5: favor this wave through the cluster
#pragma unroll
        for (int nn = 0; nn < 2; ++nn) {
            f32x16 D1 = MFMA32(kf0, qf[0][nn], zzz);   // D[m=drow][n=lane31]
            f32x16 D2 = MFMA32(kf1, qf[1][nn], zzz);
            f32x16 D3 = MFMA32(kf2, qf[2][nn], zzz);
            D1 *= D2;
            D1 *= D3;
            uint32_t p01 = pkrtz(D1[0], D1[1]),   p23 = pkrtz(D1[2], D1[3]);
            uint32_t p45 = pkrtz(D1[4], D1[5]),   p67 = pkrtz(D1[6], D1[7]);
            uint32_t p89 = pkrtz(D1[8], D1[9]),   pAB = pkrtz(D1[10], D1[11]);
            uint32_t pCD = pkrtz(D1[12], D1[13]), pEF = pkrtz(D1[14], D1[15]);
            u32x4 A1 = {p01, p23, p45, p67};
            u32x4 A2 = {p89, pAB, pCD, pEF};
            accA[nn] = MFMA32(__builtin_bit_cast(f16x8, A1), bv1, accA[nn]);
            accB[nn] = MFMA32(__builtin_bit_cast(f16x8, A2), bv2, accB[nn]);
        }
        __builtin_amdgcn_s_setprio(0);
    }

    // epilogue: acc row = n (drow), col = j (lane31, valid < 16)
    if (lane31 < 16) {
        f16* outp = OPP + (size_t)ms * 1048576;
#pragma unroll
        for (int nn = 0; nn < 2; ++nn)
#pragma unroll
            for (int reg = 0; reg < 16; ++reg) {
                int n = n0 + nn * 32 + drow(reg, l);
                outp[((size_t)(b * 2048) + n) * 256 + hb + lane31] =
                    (f16)(accA[nn][reg] + accB[nn][reg]);
            }
    }
}

// ---------------- k_final: out = LN(P0+P1) @ Wo^T + bo, 64x64 tiles ---------
// Grid (4,64) = 256 blocks -> full CU coverage. Wave-tile 32x32, 1 acc.
__global__ __launch_bounds__(256) void k_final(float* __restrict__ out, char* ws) {
    const f16* P0 = (const f16*)(ws + OFF_OPP);
    const f16* P1 = P0 + 1048576;
    const f16* Gh = (const f16*)(ws + OFF_GH);
    const float* rsg = (const float*)(ws + OFF_RSG);
    const float* B2 = (const float*)(ws + OFF_B2);

    const int ct = blockIdx.x;            // 0..3  (64 output cols)
    const int rt = blockIdx.y;            // 0..63 (64 rows)
    const int tid = threadIdx.x, l = tid & 63, w = tid >> 6;
    const int wr = w >> 1, wc = w & 1;    // wave-tile 32 rows x 32 cols

    __shared__ f16 Xl[64 * 64];
    __shared__ f16 Wl[64 * 64];
    __shared__ float muL[64], rsL[64];

    float sum[2] = {0.f, 0.f}, sumsq[2] = {0.f, 0.f};

    f32x16 acc; zero16(acc);

    for (int kt = 0; kt < 4; ++kt) {
        __syncthreads();
#pragma unroll
        for (int e = 0; e < 2; ++e) {
            int g = tid + 256 * e;        // 0..511 = 64 rows x 8 octs
            int row = g >> 3, oct = g & 7;
            size_t idx = (size_t)(rt * 64 + row) * 256 + kt * 64 + oct * 8;
            f16x8 va = *(const f16x8*)(P0 + idx);
            f16x8 vb = *(const f16x8*)(P1 + idx);
            f16x8 vx;
#pragma unroll
            for (int q = 0; q < 8; ++q) {
                float f = (float)va[q] + (float)vb[q];
                vx[q] = (f16)f;
                sum[e] += f; sumsq[e] += f * f;
            }
            stfrag(Xl, row, oct, vx);
            f16x8 vw = *(const f16x8*)(Gh + (size_t)(ct * 64 + row) * 256 + kt * 64 + oct * 8);
            stfrag(Wl, row, oct, vw);
        }
        __syncthreads();
#pragma unroll
        for (int s = 0; s < 4; ++s) {
            int g = s * 2 + (l >> 5);
            f16x8 a0 = ldfrag(Xl, wr * 32 + (l & 31), g);
            f16x8 b0 = ldfrag(Wl, wc * 32 + (l & 31), g);
            acc = MFMA32(a0, b0, acc);
        }
    }

    // row stats: 8 threads (same tid>>3) share each row; rows tid>>3, +32
#pragma unroll
    for (int e = 0; e < 2; ++e) {
#pragma unroll
        for (int off = 1; off < 8; off <<= 1) {
            sum[e] += __shfl_xor(sum[e], off);
            sumsq[e] += __shfl_xor(sumsq[e], off);
        }
    }
    if ((tid & 7) == 0) {
#pragma unroll
        for (int e = 0; e < 2; ++e) {
            int row = (tid >> 3) + 32 * e;
            float m = sum[e] * (1.f / 256.f);
            float var = sumsq[e] * (1.f / 256.f) - m * m;
            muL[row] = m;
            rsL[row] = rsqrtf(var + 1e-5f);
        }
    }
    __syncthreads();

#pragma unroll
    for (int reg = 0; reg < 16; ++reg) {
        int nloc = wr * 32 + drow(reg, l);
        int n = rt * 64 + nloc;
        int c2 = ct * 64 + wc * 32 + (l & 31);
        float v = rsL[nloc] * (acc[reg] - muL[nloc] * rsg[c2]) + B2[c2];
        out[(size_t)n * 256 + c2] = v;
    }
}

// ---------------------------------------------------------------------------
extern "C" void kernel_launch(void* const* d_in, const int* in_sizes, int n_in,
                              void* d_out, int out_size, void* d_ws, size_t ws_size,
                              hipStream_t stream) {
    (void)in_sizes; (void)n_in; (void)out_size; (void)ws_size;
    const float* x    = (const float*)d_in[0];
    const float* mask = (const float*)d_in[1];
    W7 p;
    for (int t = 0; t < 7; ++t) {
        p.W[t] = (const float*)d_in[2 + 2 * t];
        p.b[t] = (const float*)d_in[3 + 2 * t];
    }
    const float* Wo    = (const float*)d_in[16];
    const float* bo    = (const float*)d_in[17];
    const float* gamma = (const float*)d_in[18];
    const float* beta  = (const float*)d_in[19];
    char* ws = (char*)d_ws;

    const float scale = 0.14865088937534013f;   // 2048^(-0.25)

    k_prep <<<3080, 256, 0, stream>>>(x, p, scale, Wo, bo, gamma, beta, ws);
    k_lin7 <<<dim3(14, 32), 512, 0, stream>>>(mask, ws);
    k_attn <<<dim3(8, 32, 2), 256, 0, stream>>>(ws);
    k_final<<<dim3(4, 64), 256, 0, stream>>>((float*)d_out, ws);
}